// Round 10
// baseline (1167.677 us; speedup 1.0000x reference)
//
#include <hip/hip_runtime.h>
#include <cstdint>

#define TTOK 8192
#define HID  1024
#define FFD  4096
#define NEXP 8
#define NASSIGN 16384   // TTOK * 2
#define MAXMB 24        // max 128-row m-tiles/expert (cnt<=3072, r5-r9 verified)

typedef __attribute__((ext_vector_type(8))) short bf16x8;
typedef __attribute__((ext_vector_type(4))) float f32x4;

__device__ __forceinline__ unsigned short f2bf(float f) {
  unsigned int u = __builtin_bit_cast(unsigned int, f);
  u += 0x7FFFu + ((u >> 16) & 1u);           // RNE
  return (unsigned short)(u >> 16);
}

__device__ __forceinline__ float bf2f(unsigned short s) {
  unsigned int u = (unsigned int)s << 16;
  return __builtin_bit_cast(float, u);
}

__device__ __forceinline__ void gload16(const unsigned short* g, unsigned short* l) {
  __builtin_amdgcn_global_load_lds(
      (const __attribute__((address_space(1))) unsigned int*)g,
      (__attribute__((address_space(3))) unsigned int*)l, 16, 0, 0);
}

// ---------------- routing (+ x->bf16 conversion fused into gate) ----------

__global__ void zero_counts_kernel(int* counts) {
  if (threadIdx.x < NEXP) counts[threadIdx.x] = 0;
}

__global__ void gate_kernel(const float* __restrict__ x,
                            const float* __restrict__ gw,
                            const float* __restrict__ gb,
                            float* __restrict__ logits_out,
                            int* __restrict__ counts,
                            int* __restrict__ te, int* __restrict__ tp,
                            float* __restrict__ tw,
                            unsigned short* __restrict__ xb) {
  const int lane = threadIdx.x & 63;
  const int wib  = threadIdx.x >> 6;
  const int t = blockIdx.x * 4 + wib;
  const float* xr = x + (size_t)t * HID;
  unsigned short* xbr = xb + (size_t)t * HID;

  float acc[NEXP];
#pragma unroll
  for (int e = 0; e < NEXP; ++e) acc[e] = 0.f;

#pragma unroll
  for (int i = 0; i < HID / 64; ++i) {
    int h = lane + 64 * i;
    float xv = xr[h];
    xbr[h] = f2bf(xv);                         // fused convert (saves a 32MB-read pass)
    const float* g = gw + h * NEXP;
#pragma unroll
    for (int e = 0; e < NEXP; ++e) acc[e] += xv * g[e];
  }
#pragma unroll
  for (int off = 32; off; off >>= 1)
#pragma unroll
    for (int e = 0; e < NEXP; ++e) acc[e] += __shfl_xor(acc[e], off);
#pragma unroll
  for (int e = 0; e < NEXP; ++e) acc[e] += gb[e];

  if (lane < NEXP) logits_out[(size_t)t * NEXP + lane] = acc[lane];

  if (lane == 0) {
    int e0 = 0; float v0 = acc[0];
#pragma unroll
    for (int e = 1; e < NEXP; ++e) if (acc[e] > v0) { v0 = acc[e]; e0 = e; }
    int e1 = -1; float v1 = -3.4e38f;
#pragma unroll
    for (int e = 0; e < NEXP; ++e) if (e != e0 && acc[e] > v1) { v1 = acc[e]; e1 = e; }
    float s = __expf(v1 - v0);         // v1 <= v0
    float w0 = 1.f / (1.f + s);
    float w1 = s * w0;
    int p0 = atomicAdd(&counts[e0], 1);
    int p1 = atomicAdd(&counts[e1], 1);
    te[t * 2] = e0; te[t * 2 + 1] = e1;
    tp[t * 2] = p0; tp[t * 2 + 1] = p1;
    tw[t * 2] = w0; tw[t * 2 + 1] = w1;
  }
}

__global__ void scatter_kernel(const int* __restrict__ counts, int* __restrict__ offsets,
                               const int* __restrict__ te, const int* __restrict__ tp,
                               const float* __restrict__ tw,
                               int* __restrict__ tok_of, float* __restrict__ wt_of,
                               int* __restrict__ asn_of) {
  __shared__ int offs[NEXP];
  if (threadIdx.x == 0) {
    int run = 0;
    for (int e = 0; e < NEXP; ++e) { offs[e] = run; offsets[e] = run; run += counts[e]; }
  }
  __syncthreads();
  for (int t = threadIdx.x; t < TTOK; t += blockDim.x) {
#pragma unroll
    for (int j = 0; j < 2; ++j) {
      int e = te[t * 2 + j];
      int a = offs[e] + tp[t * 2 + j];
      tok_of[a] = t;
      wt_of[a] = tw[t * 2 + j];
      asn_of[t * 2 + j] = a;
    }
  }
}

// ---------------- dtype prep: all three weight transposes in ONE launch ----
// grid = (1024 tiles, 3 matrices, 8 experts); 64x64 tile, float4 in / ushort4 out.

__global__ void transpose_all_kernel(const float* __restrict__ Wg,
                                     const float* __restrict__ Wu,
                                     const float* __restrict__ Wd,
                                     unsigned short* __restrict__ WgT,
                                     unsigned short* __restrict__ WuT,
                                     unsigned short* __restrict__ WdT) {
  const int which = blockIdx.y;                // 0=Wg 1=Wu 2=Wd
  const int e = blockIdx.z;
  const float* src;
  unsigned short* dst;
  int R, C, tr, tc;
  if (which == 0)      { src = Wg; dst = WgT; R = HID; C = FFD; }
  else if (which == 1) { src = Wu; dst = WuT; R = HID; C = FFD; }
  else                 { src = Wd; dst = WdT; R = FFD; C = HID; }
  if (which < 2) { tc = blockIdx.x & 63; tr = blockIdx.x >> 6; }   // 16 x 64 tiles
  else           { tc = blockIdx.x & 15; tr = blockIdx.x >> 4; }   // 64 x 16 tiles
  const size_t base = (size_t)e * (size_t)R * C;
  src += base; dst += base;
  const int r0 = tr * 64, c0 = tc * 64;

  __shared__ float tile[64][65];
  const int tid = threadIdx.x;
  {
    const int c4 = (tid & 15) * 4, rr = tid >> 4;
#pragma unroll
    for (int i = 0; i < 4; ++i) {
      int row = rr + i * 16;
      float4 v = *(const float4*)&src[(size_t)(r0 + row) * C + c0 + c4];
      tile[row][c4 + 0] = v.x; tile[row][c4 + 1] = v.y;
      tile[row][c4 + 2] = v.z; tile[row][c4 + 3] = v.w;
    }
  }
  __syncthreads();
  {
    const int r4 = (tid & 15) * 4, cc = tid >> 4;
#pragma unroll
    for (int i = 0; i < 4; ++i) {
      int c = cc + i * 16;
      ushort4 o;
      o.x = f2bf(tile[r4 + 0][c]);
      o.y = f2bf(tile[r4 + 1][c]);
      o.z = f2bf(tile[r4 + 2][c]);
      o.w = f2bf(tile[r4 + 3][c]);
      *(ushort4*)&dst[(size_t)(c0 + c) * R + r0 + r4] = o;
    }
  }
}

// ---------------- expert GEMMs ----------------
// Round-7 proven structure (best of 5 tested schedules across r2-r9):
// 128x128 tile, BK=32, 4 waves (2x2), double-buffered LDS, 2-phase pipeline
// with counted vmcnt. e = blockIdx.x & 7 pins expert e to XCD e (consecutive
// blockIdx round-robin XCDs; r3 measured 8x weight over-fetch without this).
// launch_bounds min-waves raised to 3 (96 VGPR << 170 cap; 3x49.7KB LDS fits)
// to permit the m97-class 3-blocks/CU operating point.

__global__ __launch_bounds__(256, 3) void moe_up_kernel(
    const unsigned short* __restrict__ xb,    // [T][H] bf16
    const unsigned short* __restrict__ WgT,   // [E][F][H] bf16
    const unsigned short* __restrict__ WuT,   // [E][F][H] bf16
    const int* __restrict__ counts, const int* __restrict__ offsets,
    const int* __restrict__ tok_of,
    unsigned short* __restrict__ hbuf)        // [A][F] bf16
{
  const int e = blockIdx.x & 7;
  const int mblk = blockIdx.x >> 3;
  const int cnt = counts[e];
  if (mblk * 128 >= cnt) return;
  const int off = offsets[e];
  const int n0 = blockIdx.y * 128;

  __shared__ __align__(16) unsigned short As[2][128 * 32];
  __shared__ __align__(16) unsigned short Bgs[2][128 * 32];
  __shared__ __align__(16) unsigned short Bus[2][128 * 32];
  __shared__ int toks[128];

  const int tid = threadIdx.x;
  const int lane = tid & 63;
  const int w = tid >> 6;

  if (tid < 128) {
    int a = off + mblk * 128 + tid;
    if (a > NASSIGN - 1) a = NASSIGN - 1;
    toks[tid] = tok_of[a];
  }
  __syncthreads();

  const unsigned short* asrc[2];
  const unsigned short* bgsrc[2];
  const unsigned short* busrc[2];
#pragma unroll
  for (int j = 0; j < 2; ++j) {
    int rrow = w * 32 + j * 16 + (lane >> 2);
    int kcol = 8 * (lane & 3);
    asrc[j]  = xb  + (size_t)toks[rrow] * HID + kcol;
    bgsrc[j] = WgT + ((size_t)e * FFD + n0 + rrow) * HID + kcol;
    busrc[j] = WuT + ((size_t)e * FFD + n0 + rrow) * HID + kcol;
  }

  auto STAGE = [&](int buf, int k0) {
#pragma unroll
    for (int j = 0; j < 2; ++j) {
      gload16(asrc[j]  + k0, &As[buf][w * 1024 + j * 512]);
      gload16(bgsrc[j] + k0, &Bgs[buf][w * 1024 + j * 512]);
      gload16(busrc[j] + k0, &Bus[buf][w * 1024 + j * 512]);
    }
  };

  f32x4 accg[4][4] = {};
  f32x4 accu[4][4] = {};
  const int wr = (w >> 1) * 64, wc = (w & 1) * 64;
  const int lr = lane & 15, kg = (lane >> 4) * 8;

  STAGE(0, 0);                                 // prologue: 6 loads in flight
#pragma unroll 1
  for (int t = 0; t < HID / 32; ++t) {
    const int cur = t & 1;
    if (t + 1 < HID / 32) {
      STAGE(cur ^ 1, (t + 1) * 32);            // issue next tile (6 more loads)
      asm volatile("s_waitcnt vmcnt(6)" ::: "memory");   // tile t's 6 loads done
    } else {
      asm volatile("s_waitcnt vmcnt(0)" ::: "memory");
    }
    __builtin_amdgcn_s_barrier();              // buf[cur] ready for all waves

    bf16x8 af[4], bgf[4], buf_[4];
#pragma unroll
    for (int m = 0; m < 4; ++m)
      af[m] = *(const bf16x8*)&As[cur][(wr + m * 16 + lr) * 32 + kg];
#pragma unroll
    for (int n = 0; n < 4; ++n) {
      bgf[n]  = *(const bf16x8*)&Bgs[cur][(wc + n * 16 + lr) * 32 + kg];
      buf_[n] = *(const bf16x8*)&Bus[cur][(wc + n * 16 + lr) * 32 + kg];
    }
#pragma unroll
    for (int m = 0; m < 4; ++m)
#pragma unroll
      for (int n = 0; n < 4; ++n) {
        accg[m][n] = __builtin_amdgcn_mfma_f32_16x16x32_bf16(af[m], bgf[n],  accg[m][n], 0, 0, 0);
        accu[m][n] = __builtin_amdgcn_mfma_f32_16x16x32_bf16(af[m], buf_[n], accu[m][n], 0, 0, 0);
      }
    __builtin_amdgcn_s_barrier();              // reads of buf[cur] done before overwrite
  }

  const int crb = (lane >> 4) * 4, cc = lane & 15;
#pragma unroll
  for (int m = 0; m < 4; ++m)
#pragma unroll
    for (int n = 0; n < 4; ++n)
#pragma unroll
      for (int r = 0; r < 4; ++r) {
        int lrow = wr + m * 16 + crb + r;
        int grow = mblk * 128 + lrow;
        if (grow < cnt) {
          size_t a = (size_t)off + grow;
          float g = accg[m][n][r];
          float u = accu[m][n][r];
          float sg = g / (1.0f + __expf(-g));   // silu
          hbuf[a * FFD + (n0 + wc + n * 16 + cc)] = f2bf(sg * u);
        }
      }
}

__global__ __launch_bounds__(256, 3) void moe_down_kernel(
    const unsigned short* __restrict__ hb,    // [A][F] bf16
    const unsigned short* __restrict__ WdT,   // [E][H][F] bf16
    const int* __restrict__ counts, const int* __restrict__ offsets,
    unsigned short* __restrict__ ypart)       // [A][H] bf16
{
  const int e = blockIdx.x & 7;
  const int mblk = blockIdx.x >> 3;
  const int cnt = counts[e];
  if (mblk * 128 >= cnt) return;
  const int off = offsets[e];
  const int n0 = blockIdx.y * 128;

  __shared__ __align__(16) unsigned short As[2][128 * 32];
  __shared__ __align__(16) unsigned short Bs[2][128 * 32];

  const int tid = threadIdx.x;
  const int lane = tid & 63;
  const int w = tid >> 6;

  const unsigned short* asrc[2];
  const unsigned short* bsrc[2];
#pragma unroll
  for (int j = 0; j < 2; ++j) {
    int rrow = w * 32 + j * 16 + (lane >> 2);
    int kcol = 8 * (lane & 3);
    int a = off + mblk * 128 + rrow;
    if (a > NASSIGN - 1) a = NASSIGN - 1;
    asrc[j] = hb + (size_t)a * FFD + kcol;
    bsrc[j] = WdT + ((size_t)e * HID + n0 + rrow) * FFD + kcol;
  }

  auto STAGE = [&](int buf, int k0) {
#pragma unroll
    for (int j = 0; j < 2; ++j) {
      gload16(asrc[j] + k0, &As[buf][w * 1024 + j * 512]);
      gload16(bsrc[j] + k0, &Bs[buf][w * 1024 + j * 512]);
    }
  };

  f32x4 acc[4][4] = {};
  const int wr = (w >> 1) * 64, wc = (w & 1) * 64;
  const int lr = lane & 15, kg = (lane >> 4) * 8;

  STAGE(0, 0);                                 // prologue: 4 loads in flight
#pragma unroll 1
  for (int t = 0; t < FFD / 32; ++t) {
    const int cur = t & 1;
    if (t + 1 < FFD / 32) {
      STAGE(cur ^ 1, (t + 1) * 32);            // +4 loads
      asm volatile("s_waitcnt vmcnt(4)" ::: "memory");   // tile t's 4 loads done
    } else {
      asm volatile("s_waitcnt vmcnt(0)" ::: "memory");
    }
    __builtin_amdgcn_s_barrier();

    bf16x8 af[4], bf_[4];
#pragma unroll
    for (int m = 0; m < 4; ++m)
      af[m] = *(const bf16x8*)&As[cur][(wr + m * 16 + lr) * 32 + kg];
#pragma unroll
    for (int n = 0; n < 4; ++n)
      bf_[n] = *(const bf16x8*)&Bs[cur][(wc + n * 16 + lr) * 32 + kg];
#pragma unroll
    for (int m = 0; m < 4; ++m)
#pragma unroll
      for (int n = 0; n < 4; ++n)
        acc[m][n] = __builtin_amdgcn_mfma_f32_16x16x32_bf16(af[m], bf_[n], acc[m][n], 0, 0, 0);
    __builtin_amdgcn_s_barrier();
  }

  const int crb = (lane >> 4) * 4, cc = lane & 15;
#pragma unroll
  for (int m = 0; m < 4; ++m)
#pragma unroll
    for (int n = 0; n < 4; ++n)
#pragma unroll
      for (int r = 0; r < 4; ++r) {
        int lrow = wr + m * 16 + crb + r;
        int grow = mblk * 128 + lrow;
        if (grow < cnt)
          ypart[((size_t)off + grow) * HID + (n0 + wc + n * 16 + cc)] = f2bf(acc[m][n][r]);
      }
}

__global__ void combine_kernel(const unsigned short* __restrict__ ypart,  // [A][H] bf16
                               const int* __restrict__ asn_of,
                               const float* __restrict__ wt_of,
                               float* __restrict__ y) {
  const int t = blockIdx.x;
  const int a0 = asn_of[t * 2], a1 = asn_of[t * 2 + 1];
  const float w0 = wt_of[a0], w1 = wt_of[a1];
  const int c = threadIdx.x * 4;
  ushort4 p0 = *(const ushort4*)&ypart[(size_t)a0 * HID + c];
  ushort4 p1 = *(const ushort4*)&ypart[(size_t)a1 * HID + c];
  float4 r;
  r.x = w0 * bf2f(p0.x) + w1 * bf2f(p1.x);
  r.y = w0 * bf2f(p0.y) + w1 * bf2f(p1.y);
  r.z = w0 * bf2f(p0.z) + w1 * bf2f(p1.z);
  r.w = w0 * bf2f(p0.w) + w1 * bf2f(p1.w);
  *(float4*)&y[(size_t)t * HID + c] = r;
}

// ---------------- launch ----------------

extern "C" void kernel_launch(void* const* d_in, const int* in_sizes, int n_in,
                              void* d_out, int out_size, void* d_ws, size_t ws_size,
                              hipStream_t stream) {
  const float* x  = (const float*)d_in[0];
  const float* gw = (const float*)d_in[1];
  const float* gb = (const float*)d_in[2];
  const float* Wg = (const float*)d_in[3];
  const float* Wu = (const float*)d_in[4];
  const float* Wd = (const float*)d_in[5];
  float* out = (float*)d_out;
  float* logits = out + (size_t)TTOK * HID;

  char* ws = (char*)d_ws;
  size_t o = 0;
  auto carve = [&](size_t b) { char* p = ws + o; o += (b + 255) & ~(size_t)255; return p; };
  int*   counts  = (int*)carve(NEXP * 4);
  int*   offsets = (int*)carve(NEXP * 4);
  int*   te      = (int*)carve((size_t)TTOK * 2 * 4);
  int*   tp      = (int*)carve((size_t)TTOK * 2 * 4);
  float* tw      = (float*)carve((size_t)TTOK * 2 * 4);
  int*   tok_of  = (int*)carve((size_t)NASSIGN * 4);
  float* wt_of   = (float*)carve((size_t)NASSIGN * 4);
  int*   asn_of  = (int*)carve((size_t)TTOK * 2 * 4);
  unsigned short* xb  = (unsigned short*)carve((size_t)TTOK * HID * 2);
  unsigned short* WgT = (unsigned short*)carve((size_t)NEXP * FFD * HID * 2);
  unsigned short* WuT = (unsigned short*)carve((size_t)NEXP * FFD * HID * 2);
  unsigned short* WdT = (unsigned short*)carve((size_t)NEXP * HID * FFD * 2);
  unsigned short* hb  = (unsigned short*)carve((size_t)NASSIGN * FFD * 2);
  unsigned short* ypart = (unsigned short*)carve((size_t)NASSIGN * HID * 2);
  (void)ws_size; (void)in_sizes; (void)n_in; (void)out_size;

  zero_counts_kernel<<<dim3(1), dim3(64), 0, stream>>>(counts);
  gate_kernel<<<dim3(TTOK / 4), dim3(256), 0, stream>>>(x, gw, gb, logits, counts, te, tp, tw, xb);
  scatter_kernel<<<dim3(1), dim3(256), 0, stream>>>(counts, offsets, te, tp, tw, tok_of, wt_of, asn_of);
  transpose_all_kernel<<<dim3(1024, 3, NEXP), dim3(256), 0, stream>>>(Wg, Wu, Wd, WgT, WuT, WdT);
  // grid.x = 8 experts * MAXMB m-tiles; x%8 = expert = XCD (192 % 8 == 0)
  moe_up_kernel<<<dim3(NEXP * MAXMB, FFD / 128), dim3(256), 0, stream>>>(xb, WgT, WuT, counts, offsets, tok_of, hb);
  moe_down_kernel<<<dim3(NEXP * MAXMB, HID / 128), dim3(256), 0, stream>>>(hb, WdT, counts, offsets, ypart);
  combine_kernel<<<dim3(TTOK), dim3(256), 0, stream>>>(ypart, asn_of, wt_of, out);
}

// Round 11
// 965.342 us; speedup vs baseline: 1.2096x; 1.2096x over previous
//
#include <hip/hip_runtime.h>
#include <cstdint>

#define TTOK 8192
#define HID  1024
#define FFD  4096
#define NEXP 8
#define NASSIGN 16384   // TTOK * 2
#define MAXMB 24        // max 128-row m-tiles/expert (cnt<=3072, r5-r10 verified)

typedef __attribute__((ext_vector_type(8))) short bf16x8;
typedef __attribute__((ext_vector_type(4))) float f32x4;

__device__ __forceinline__ unsigned short f2bf(float f) {
  unsigned int u = __builtin_bit_cast(unsigned int, f);
  u += 0x7FFFu + ((u >> 16) & 1u);           // RNE
  return (unsigned short)(u >> 16);
}

__device__ __forceinline__ float bf2f(unsigned short s) {
  unsigned int u = (unsigned int)s << 16;
  return __builtin_bit_cast(float, u);
}

__device__ __forceinline__ void gload16(const unsigned short* g, unsigned short* l) {
  __builtin_amdgcn_global_load_lds(
      (const __attribute__((address_space(1))) unsigned int*)g,
      (__attribute__((address_space(3))) unsigned int*)l, 16, 0, 0);
}

// ---------------- routing (+ x->bf16 conversion fused into gate) ----------

__global__ void zero_counts_kernel(int* counts) {
  if (threadIdx.x < NEXP) counts[threadIdx.x] = 0;
}

__global__ void gate_kernel(const float* __restrict__ x,
                            const float* __restrict__ gw,
                            const float* __restrict__ gb,
                            float* __restrict__ logits_out,
                            int* __restrict__ counts,
                            int* __restrict__ te, int* __restrict__ tp,
                            float* __restrict__ tw,
                            unsigned short* __restrict__ xb) {
  const int lane = threadIdx.x & 63;
  const int wib  = threadIdx.x >> 6;
  const int t = blockIdx.x * 4 + wib;
  const float* xr = x + (size_t)t * HID;
  unsigned short* xbr = xb + (size_t)t * HID;

  float acc[NEXP];
#pragma unroll
  for (int e = 0; e < NEXP; ++e) acc[e] = 0.f;

#pragma unroll
  for (int i = 0; i < HID / 64; ++i) {
    int h = lane + 64 * i;
    float xv = xr[h];
    xbr[h] = f2bf(xv);                         // fused convert (saves a 32MB-read pass)
    const float* g = gw + h * NEXP;
#pragma unroll
    for (int e = 0; e < NEXP; ++e) acc[e] += xv * g[e];
  }
#pragma unroll
  for (int off = 32; off; off >>= 1)
#pragma unroll
    for (int e = 0; e < NEXP; ++e) acc[e] += __shfl_xor(acc[e], off);
#pragma unroll
  for (int e = 0; e < NEXP; ++e) acc[e] += gb[e];

  if (lane < NEXP) logits_out[(size_t)t * NEXP + lane] = acc[lane];

  if (lane == 0) {
    int e0 = 0; float v0 = acc[0];
#pragma unroll
    for (int e = 1; e < NEXP; ++e) if (acc[e] > v0) { v0 = acc[e]; e0 = e; }
    int e1 = -1; float v1 = -3.4e38f;
#pragma unroll
    for (int e = 0; e < NEXP; ++e) if (e != e0 && acc[e] > v1) { v1 = acc[e]; e1 = e; }
    float s = __expf(v1 - v0);         // v1 <= v0
    float w0 = 1.f / (1.f + s);
    float w1 = s * w0;
    int p0 = atomicAdd(&counts[e0], 1);
    int p1 = atomicAdd(&counts[e1], 1);
    te[t * 2] = e0; te[t * 2 + 1] = e1;
    tp[t * 2] = p0; tp[t * 2 + 1] = p1;
    tw[t * 2] = w0; tw[t * 2 + 1] = w1;
  }
}

__global__ void scatter_kernel(const int* __restrict__ counts, int* __restrict__ offsets,
                               const int* __restrict__ te, const int* __restrict__ tp,
                               const float* __restrict__ tw,
                               int* __restrict__ tok_of, float* __restrict__ wt_of,
                               int* __restrict__ asn_of) {
  __shared__ int offs[NEXP];
  if (threadIdx.x == 0) {
    int run = 0;
    for (int e = 0; e < NEXP; ++e) { offs[e] = run; offsets[e] = run; run += counts[e]; }
  }
  __syncthreads();
  for (int t = threadIdx.x; t < TTOK; t += blockDim.x) {
#pragma unroll
    for (int j = 0; j < 2; ++j) {
      int e = te[t * 2 + j];
      int a = offs[e] + tp[t * 2 + j];
      tok_of[a] = t;
      wt_of[a] = tw[t * 2 + j];
      asn_of[t * 2 + j] = a;
    }
  }
}

// ---------------- dtype prep: all three weight transposes in ONE launch ----
// grid = (1024 tiles, 3 matrices, 8 experts); 64x64 tile, float4 in / ushort4 out.

__global__ void transpose_all_kernel(const float* __restrict__ Wg,
                                     const float* __restrict__ Wu,
                                     const float* __restrict__ Wd,
                                     unsigned short* __restrict__ WgT,
                                     unsigned short* __restrict__ WuT,
                                     unsigned short* __restrict__ WdT) {
  const int which = blockIdx.y;                // 0=Wg 1=Wu 2=Wd
  const int e = blockIdx.z;
  const float* src;
  unsigned short* dst;
  int R, C, tr, tc;
  if (which == 0)      { src = Wg; dst = WgT; R = HID; C = FFD; }
  else if (which == 1) { src = Wu; dst = WuT; R = HID; C = FFD; }
  else                 { src = Wd; dst = WdT; R = FFD; C = HID; }
  if (which < 2) { tc = blockIdx.x & 63; tr = blockIdx.x >> 6; }   // 16 x 64 tiles
  else           { tc = blockIdx.x & 15; tr = blockIdx.x >> 4; }   // 64 x 16 tiles
  const size_t base = (size_t)e * (size_t)R * C;
  src += base; dst += base;
  const int r0 = tr * 64, c0 = tc * 64;

  __shared__ float tile[64][65];
  const int tid = threadIdx.x;
  {
    const int c4 = (tid & 15) * 4, rr = tid >> 4;
#pragma unroll
    for (int i = 0; i < 4; ++i) {
      int row = rr + i * 16;
      float4 v = *(const float4*)&src[(size_t)(r0 + row) * C + c0 + c4];
      tile[row][c4 + 0] = v.x; tile[row][c4 + 1] = v.y;
      tile[row][c4 + 2] = v.z; tile[row][c4 + 3] = v.w;
    }
  }
  __syncthreads();
  {
    const int r4 = (tid & 15) * 4, cc = tid >> 4;
#pragma unroll
    for (int i = 0; i < 4; ++i) {
      int c = cc + i * 16;
      ushort4 o;
      o.x = f2bf(tile[r4 + 0][c]);
      o.y = f2bf(tile[r4 + 1][c]);
      o.z = f2bf(tile[r4 + 2][c]);
      o.w = f2bf(tile[r4 + 3][c]);
      *(ushort4*)&dst[(size_t)(c0 + c) * R + r0 + r4] = o;
    }
  }
}

// ---------------- expert GEMMs ----------------
// Round-7 proven structure (best of all schedules tested r2-r10): 128x128
// tile, BK=32, 4 waves (2x2), double-buffered LDS, 2-phase pipeline with
// counted vmcnt, __launch_bounds__(256,2). r10 lesson: (256,3) raises
// occupancy to 3 blocks/CU but blows the per-XCD L2 write working set
// (WRITE_SIZE 131->211 MB, BW drops to 700 GB/s, dur +45%) — 2 blocks/CU
// is the right operating point. e = blockIdx.x & 7 pins expert e to XCD e
// (consecutive blockIdx round-robin XCDs; r3 measured 8x weight over-fetch
// without this).

__global__ __launch_bounds__(256, 2) void moe_up_kernel(
    const unsigned short* __restrict__ xb,    // [T][H] bf16
    const unsigned short* __restrict__ WgT,   // [E][F][H] bf16
    const unsigned short* __restrict__ WuT,   // [E][F][H] bf16
    const int* __restrict__ counts, const int* __restrict__ offsets,
    const int* __restrict__ tok_of,
    unsigned short* __restrict__ hbuf)        // [A][F] bf16
{
  const int e = blockIdx.x & 7;
  const int mblk = blockIdx.x >> 3;
  const int cnt = counts[e];
  if (mblk * 128 >= cnt) return;
  const int off = offsets[e];
  const int n0 = blockIdx.y * 128;

  __shared__ __align__(16) unsigned short As[2][128 * 32];
  __shared__ __align__(16) unsigned short Bgs[2][128 * 32];
  __shared__ __align__(16) unsigned short Bus[2][128 * 32];
  __shared__ int toks[128];

  const int tid = threadIdx.x;
  const int lane = tid & 63;
  const int w = tid >> 6;

  if (tid < 128) {
    int a = off + mblk * 128 + tid;
    if (a > NASSIGN - 1) a = NASSIGN - 1;
    toks[tid] = tok_of[a];
  }
  __syncthreads();

  const unsigned short* asrc[2];
  const unsigned short* bgsrc[2];
  const unsigned short* busrc[2];
#pragma unroll
  for (int j = 0; j < 2; ++j) {
    int rrow = w * 32 + j * 16 + (lane >> 2);
    int kcol = 8 * (lane & 3);
    asrc[j]  = xb  + (size_t)toks[rrow] * HID + kcol;
    bgsrc[j] = WgT + ((size_t)e * FFD + n0 + rrow) * HID + kcol;
    busrc[j] = WuT + ((size_t)e * FFD + n0 + rrow) * HID + kcol;
  }

  auto STAGE = [&](int buf, int k0) {
#pragma unroll
    for (int j = 0; j < 2; ++j) {
      gload16(asrc[j]  + k0, &As[buf][w * 1024 + j * 512]);
      gload16(bgsrc[j] + k0, &Bgs[buf][w * 1024 + j * 512]);
      gload16(busrc[j] + k0, &Bus[buf][w * 1024 + j * 512]);
    }
  };

  f32x4 accg[4][4] = {};
  f32x4 accu[4][4] = {};
  const int wr = (w >> 1) * 64, wc = (w & 1) * 64;
  const int lr = lane & 15, kg = (lane >> 4) * 8;

  STAGE(0, 0);                                 // prologue: 6 loads in flight
#pragma unroll 1
  for (int t = 0; t < HID / 32; ++t) {
    const int cur = t & 1;
    if (t + 1 < HID / 32) {
      STAGE(cur ^ 1, (t + 1) * 32);            // issue next tile (6 more loads)
      asm volatile("s_waitcnt vmcnt(6)" ::: "memory");   // tile t's 6 loads done
    } else {
      asm volatile("s_waitcnt vmcnt(0)" ::: "memory");
    }
    __builtin_amdgcn_s_barrier();              // buf[cur] ready for all waves

    bf16x8 af[4], bgf[4], buf_[4];
#pragma unroll
    for (int m = 0; m < 4; ++m)
      af[m] = *(const bf16x8*)&As[cur][(wr + m * 16 + lr) * 32 + kg];
#pragma unroll
    for (int n = 0; n < 4; ++n) {
      bgf[n]  = *(const bf16x8*)&Bgs[cur][(wc + n * 16 + lr) * 32 + kg];
      buf_[n] = *(const bf16x8*)&Bus[cur][(wc + n * 16 + lr) * 32 + kg];
    }
#pragma unroll
    for (int m = 0; m < 4; ++m)
#pragma unroll
      for (int n = 0; n < 4; ++n) {
        accg[m][n] = __builtin_amdgcn_mfma_f32_16x16x32_bf16(af[m], bgf[n],  accg[m][n], 0, 0, 0);
        accu[m][n] = __builtin_amdgcn_mfma_f32_16x16x32_bf16(af[m], buf_[n], accu[m][n], 0, 0, 0);
      }
    __builtin_amdgcn_s_barrier();              // reads of buf[cur] done before overwrite
  }

  const int crb = (lane >> 4) * 4, cc = lane & 15;
#pragma unroll
  for (int m = 0; m < 4; ++m)
#pragma unroll
    for (int n = 0; n < 4; ++n)
#pragma unroll
      for (int r = 0; r < 4; ++r) {
        int lrow = wr + m * 16 + crb + r;
        int grow = mblk * 128 + lrow;
        if (grow < cnt) {
          size_t a = (size_t)off + grow;
          float g = accg[m][n][r];
          float u = accu[m][n][r];
          float sg = g / (1.0f + __expf(-g));   // silu
          hbuf[a * FFD + (n0 + wc + n * 16 + cc)] = f2bf(sg * u);
        }
      }
}

__global__ __launch_bounds__(256, 2) void moe_down_kernel(
    const unsigned short* __restrict__ hb,    // [A][F] bf16
    const unsigned short* __restrict__ WdT,   // [E][H][F] bf16
    const int* __restrict__ counts, const int* __restrict__ offsets,
    unsigned short* __restrict__ ypart)       // [A][H] bf16
{
  const int e = blockIdx.x & 7;
  const int mblk = blockIdx.x >> 3;
  const int cnt = counts[e];
  if (mblk * 128 >= cnt) return;
  const int off = offsets[e];
  const int n0 = blockIdx.y * 128;

  __shared__ __align__(16) unsigned short As[2][128 * 32];
  __shared__ __align__(16) unsigned short Bs[2][128 * 32];

  const int tid = threadIdx.x;
  const int lane = tid & 63;
  const int w = tid >> 6;

  const unsigned short* asrc[2];
  const unsigned short* bsrc[2];
#pragma unroll
  for (int j = 0; j < 2; ++j) {
    int rrow = w * 32 + j * 16 + (lane >> 2);
    int kcol = 8 * (lane & 3);
    int a = off + mblk * 128 + rrow;
    if (a > NASSIGN - 1) a = NASSIGN - 1;
    asrc[j] = hb + (size_t)a * FFD + kcol;
    bsrc[j] = WdT + ((size_t)e * HID + n0 + rrow) * FFD + kcol;
  }

  auto STAGE = [&](int buf, int k0) {
#pragma unroll
    for (int j = 0; j < 2; ++j) {
      gload16(asrc[j] + k0, &As[buf][w * 1024 + j * 512]);
      gload16(bsrc[j] + k0, &Bs[buf][w * 1024 + j * 512]);
    }
  };

  f32x4 acc[4][4] = {};
  const int wr = (w >> 1) * 64, wc = (w & 1) * 64;
  const int lr = lane & 15, kg = (lane >> 4) * 8;

  STAGE(0, 0);                                 // prologue: 4 loads in flight
#pragma unroll 1
  for (int t = 0; t < FFD / 32; ++t) {
    const int cur = t & 1;
    if (t + 1 < FFD / 32) {
      STAGE(cur ^ 1, (t + 1) * 32);            // +4 loads
      asm volatile("s_waitcnt vmcnt(4)" ::: "memory");   // tile t's 4 loads done
    } else {
      asm volatile("s_waitcnt vmcnt(0)" ::: "memory");
    }
    __builtin_amdgcn_s_barrier();

    bf16x8 af[4], bf_[4];
#pragma unroll
    for (int m = 0; m < 4; ++m)
      af[m] = *(const bf16x8*)&As[cur][(wr + m * 16 + lr) * 32 + kg];
#pragma unroll
    for (int n = 0; n < 4; ++n)
      bf_[n] = *(const bf16x8*)&Bs[cur][(wc + n * 16 + lr) * 32 + kg];
#pragma unroll
    for (int m = 0; m < 4; ++m)
#pragma unroll
      for (int n = 0; n < 4; ++n)
        acc[m][n] = __builtin_amdgcn_mfma_f32_16x16x32_bf16(af[m], bf_[n], acc[m][n], 0, 0, 0);
    __builtin_amdgcn_s_barrier();
  }

  const int crb = (lane >> 4) * 4, cc = lane & 15;
#pragma unroll
  for (int m = 0; m < 4; ++m)
#pragma unroll
    for (int n = 0; n < 4; ++n)
#pragma unroll
      for (int r = 0; r < 4; ++r) {
        int lrow = wr + m * 16 + crb + r;
        int grow = mblk * 128 + lrow;
        if (grow < cnt)
          ypart[((size_t)off + grow) * HID + (n0 + wc + n * 16 + cc)] = f2bf(acc[m][n][r]);
      }
}

__global__ void combine_kernel(const unsigned short* __restrict__ ypart,  // [A][H] bf16
                               const int* __restrict__ asn_of,
                               const float* __restrict__ wt_of,
                               float* __restrict__ y) {
  const int t = blockIdx.x;
  const int a0 = asn_of[t * 2], a1 = asn_of[t * 2 + 1];
  const float w0 = wt_of[a0], w1 = wt_of[a1];
  const int c = threadIdx.x * 4;
  ushort4 p0 = *(const ushort4*)&ypart[(size_t)a0 * HID + c];
  ushort4 p1 = *(const ushort4*)&ypart[(size_t)a1 * HID + c];
  float4 r;
  r.x = w0 * bf2f(p0.x) + w1 * bf2f(p1.x);
  r.y = w0 * bf2f(p0.y) + w1 * bf2f(p1.y);
  r.z = w0 * bf2f(p0.z) + w1 * bf2f(p1.z);
  r.w = w0 * bf2f(p0.w) + w1 * bf2f(p1.w);
  *(float4*)&y[(size_t)t * HID + c] = r;
}

// ---------------- launch ----------------

extern "C" void kernel_launch(void* const* d_in, const int* in_sizes, int n_in,
                              void* d_out, int out_size, void* d_ws, size_t ws_size,
                              hipStream_t stream) {
  const float* x  = (const float*)d_in[0];
  const float* gw = (const float*)d_in[1];
  const float* gb = (const float*)d_in[2];
  const float* Wg = (const float*)d_in[3];
  const float* Wu = (const float*)d_in[4];
  const float* Wd = (const float*)d_in[5];
  float* out = (float*)d_out;
  float* logits = out + (size_t)TTOK * HID;

  char* ws = (char*)d_ws;
  size_t o = 0;
  auto carve = [&](size_t b) { char* p = ws + o; o += (b + 255) & ~(size_t)255; return p; };
  int*   counts  = (int*)carve(NEXP * 4);
  int*   offsets = (int*)carve(NEXP * 4);
  int*   te      = (int*)carve((size_t)TTOK * 2 * 4);
  int*   tp      = (int*)carve((size_t)TTOK * 2 * 4);
  float* tw      = (float*)carve((size_t)TTOK * 2 * 4);
  int*   tok_of  = (int*)carve((size_t)NASSIGN * 4);
  float* wt_of   = (float*)carve((size_t)NASSIGN * 4);
  int*   asn_of  = (int*)carve((size_t)TTOK * 2 * 4);
  unsigned short* xb  = (unsigned short*)carve((size_t)TTOK * HID * 2);
  unsigned short* WgT = (unsigned short*)carve((size_t)NEXP * FFD * HID * 2);
  unsigned short* WuT = (unsigned short*)carve((size_t)NEXP * FFD * HID * 2);
  unsigned short* WdT = (unsigned short*)carve((size_t)NEXP * HID * FFD * 2);
  unsigned short* hb  = (unsigned short*)carve((size_t)NASSIGN * FFD * 2);
  unsigned short* ypart = (unsigned short*)carve((size_t)NASSIGN * HID * 2);
  (void)ws_size; (void)in_sizes; (void)n_in; (void)out_size;

  zero_counts_kernel<<<dim3(1), dim3(64), 0, stream>>>(counts);
  gate_kernel<<<dim3(TTOK / 4), dim3(256), 0, stream>>>(x, gw, gb, logits, counts, te, tp, tw, xb);
  scatter_kernel<<<dim3(1), dim3(256), 0, stream>>>(counts, offsets, te, tp, tw, tok_of, wt_of, asn_of);
  transpose_all_kernel<<<dim3(1024, 3, NEXP), dim3(256), 0, stream>>>(Wg, Wu, Wd, WgT, WuT, WdT);
  // grid.x = 8 experts * MAXMB m-tiles; x%8 = expert = XCD (192 % 8 == 0)
  moe_up_kernel<<<dim3(NEXP * MAXMB, FFD / 128), dim3(256), 0, stream>>>(xb, WgT, WuT, counts, offsets, tok_of, hb);
  moe_down_kernel<<<dim3(NEXP * MAXMB, HID / 128), dim3(256), 0, stream>>>(hb, WdT, counts, offsets, ypart);
  combine_kernel<<<dim3(TTOK), dim3(256), 0, stream>>>(ypart, asn_of, wt_of, out);
}

// Round 12
// 945.657 us; speedup vs baseline: 1.2348x; 1.0208x over previous
//
#include <hip/hip_runtime.h>
#include <cstdint>

#define TTOK 8192
#define HID  1024
#define FFD  4096
#define NEXP 8
#define NASSIGN 16384   // TTOK * 2
#define MAXMB 24        // max 128-row m-tiles/expert (cnt<=3072, r5-r11 verified)
#define MCAP 12         // max 256-row m-groups/expert

typedef __attribute__((ext_vector_type(8))) short bf16x8;
typedef __attribute__((ext_vector_type(4))) float f32x4;

__device__ __forceinline__ unsigned short f2bf(float f) {
  unsigned int u = __builtin_bit_cast(unsigned int, f);
  u += 0x7FFFu + ((u >> 16) & 1u);           // RNE
  return (unsigned short)(u >> 16);
}

__device__ __forceinline__ float bf2f(unsigned short s) {
  unsigned int u = (unsigned int)s << 16;
  return __builtin_bit_cast(float, u);
}

__device__ __forceinline__ void gload16(const unsigned short* g, unsigned short* l) {
  __builtin_amdgcn_global_load_lds(
      (const __attribute__((address_space(1))) unsigned int*)g,
      (__attribute__((address_space(3))) unsigned int*)l, 16, 0, 0);
}

// ---------------- routing (+ x->bf16 conversion fused into gate) ----------

__global__ void zero_counts_kernel(int* counts) {
  if (threadIdx.x < NEXP) counts[threadIdx.x] = 0;
}

__global__ void gate_kernel(const float* __restrict__ x,
                            const float* __restrict__ gw,
                            const float* __restrict__ gb,
                            float* __restrict__ logits_out,
                            int* __restrict__ counts,
                            int* __restrict__ te, int* __restrict__ tp,
                            float* __restrict__ tw,
                            unsigned short* __restrict__ xb) {
  const int lane = threadIdx.x & 63;
  const int wib  = threadIdx.x >> 6;
  const int t = blockIdx.x * 4 + wib;
  const float* xr = x + (size_t)t * HID;
  unsigned short* xbr = xb + (size_t)t * HID;

  float acc[NEXP];
#pragma unroll
  for (int e = 0; e < NEXP; ++e) acc[e] = 0.f;

#pragma unroll
  for (int i = 0; i < HID / 64; ++i) {
    int h = lane + 64 * i;
    float xv = xr[h];
    xbr[h] = f2bf(xv);                         // fused convert (saves a 32MB-read pass)
    const float* g = gw + h * NEXP;
#pragma unroll
    for (int e = 0; e < NEXP; ++e) acc[e] += xv * g[e];
  }
#pragma unroll
  for (int off = 32; off; off >>= 1)
#pragma unroll
    for (int e = 0; e < NEXP; ++e) acc[e] += __shfl_xor(acc[e], off);
#pragma unroll
  for (int e = 0; e < NEXP; ++e) acc[e] += gb[e];

  if (lane < NEXP) logits_out[(size_t)t * NEXP + lane] = acc[lane];

  if (lane == 0) {
    int e0 = 0; float v0 = acc[0];
#pragma unroll
    for (int e = 1; e < NEXP; ++e) if (acc[e] > v0) { v0 = acc[e]; e0 = e; }
    int e1 = -1; float v1 = -3.4e38f;
#pragma unroll
    for (int e = 0; e < NEXP; ++e) if (e != e0 && acc[e] > v1) { v1 = acc[e]; e1 = e; }
    float s = __expf(v1 - v0);         // v1 <= v0
    float w0 = 1.f / (1.f + s);
    float w1 = s * w0;
    int p0 = atomicAdd(&counts[e0], 1);
    int p1 = atomicAdd(&counts[e1], 1);
    te[t * 2] = e0; te[t * 2 + 1] = e1;
    tp[t * 2] = p0; tp[t * 2 + 1] = p1;
    tw[t * 2] = w0; tw[t * 2 + 1] = w1;
  }
}

__global__ void scatter_kernel(const int* __restrict__ counts, int* __restrict__ offsets,
                               const int* __restrict__ te, const int* __restrict__ tp,
                               const float* __restrict__ tw,
                               int* __restrict__ tok_of, float* __restrict__ wt_of,
                               int* __restrict__ asn_of) {
  __shared__ int offs[NEXP];
  if (threadIdx.x == 0) {
    int run = 0;
    for (int e = 0; e < NEXP; ++e) { offs[e] = run; offsets[e] = run; run += counts[e]; }
  }
  __syncthreads();
  for (int t = threadIdx.x; t < TTOK; t += blockDim.x) {
#pragma unroll
    for (int j = 0; j < 2; ++j) {
      int e = te[t * 2 + j];
      int a = offs[e] + tp[t * 2 + j];
      tok_of[a] = t;
      wt_of[a] = tw[t * 2 + j];
      asn_of[t * 2 + j] = a;
    }
  }
}

// ---------------- dtype prep: all three weight transposes in ONE launch ----
// grid = (1024 tiles, 3 matrices, 8 experts); 64x64 tile, float4 in / ushort4 out.

__global__ void transpose_all_kernel(const float* __restrict__ Wg,
                                     const float* __restrict__ Wu,
                                     const float* __restrict__ Wd,
                                     unsigned short* __restrict__ WgT,
                                     unsigned short* __restrict__ WuT,
                                     unsigned short* __restrict__ WdT) {
  const int which = blockIdx.y;                // 0=Wg 1=Wu 2=Wd
  const int e = blockIdx.z;
  const float* src;
  unsigned short* dst;
  int R, C, tr, tc;
  if (which == 0)      { src = Wg; dst = WgT; R = HID; C = FFD; }
  else if (which == 1) { src = Wu; dst = WuT; R = HID; C = FFD; }
  else                 { src = Wd; dst = WdT; R = FFD; C = HID; }
  if (which < 2) { tc = blockIdx.x & 63; tr = blockIdx.x >> 6; }   // 16 x 64 tiles
  else           { tc = blockIdx.x & 15; tr = blockIdx.x >> 4; }   // 64 x 16 tiles
  const size_t base = (size_t)e * (size_t)R * C;
  src += base; dst += base;
  const int r0 = tr * 64, c0 = tc * 64;

  __shared__ float tile[64][65];
  const int tid = threadIdx.x;
  {
    const int c4 = (tid & 15) * 4, rr = tid >> 4;
#pragma unroll
    for (int i = 0; i < 4; ++i) {
      int row = rr + i * 16;
      float4 v = *(const float4*)&src[(size_t)(r0 + row) * C + c0 + c4];
      tile[row][c4 + 0] = v.x; tile[row][c4 + 1] = v.y;
      tile[row][c4 + 2] = v.z; tile[row][c4 + 3] = v.w;
    }
  }
  __syncthreads();
  {
    const int r4 = (tid & 15) * 4, cc = tid >> 4;
#pragma unroll
    for (int i = 0; i < 4; ++i) {
      int c = cc + i * 16;
      ushort4 o;
      o.x = f2bf(tile[r4 + 0][c]);
      o.y = f2bf(tile[r4 + 1][c]);
      o.z = f2bf(tile[r4 + 2][c]);
      o.w = f2bf(tile[r4 + 3][c]);
      *(ushort4*)&dst[(size_t)(c0 + c) * R + r0 + r4] = o;
    }
  }
}

// ---------------- up GEMM: round-7/11 proven structure ----------------
// 128x128 tile, BK=32, 4 waves (2x2), double-buffered LDS, 2-phase pipeline
// with counted vmcnt, __launch_bounds__(256,2) (r10: (256,3) blows L2 write
// working set, +45% dur). e = blockIdx.x & 7 pins expert e to XCD e.

__global__ __launch_bounds__(256, 2) void moe_up_kernel(
    const unsigned short* __restrict__ xb,    // [T][H] bf16
    const unsigned short* __restrict__ WgT,   // [E][F][H] bf16
    const unsigned short* __restrict__ WuT,   // [E][F][H] bf16
    const int* __restrict__ counts, const int* __restrict__ offsets,
    const int* __restrict__ tok_of,
    unsigned short* __restrict__ hbuf)        // [A][F] bf16
{
  const int e = blockIdx.x & 7;
  const int mblk = blockIdx.x >> 3;
  const int cnt = counts[e];
  if (mblk * 128 >= cnt) return;
  const int off = offsets[e];
  const int n0 = blockIdx.y * 128;

  __shared__ __align__(16) unsigned short As[2][128 * 32];
  __shared__ __align__(16) unsigned short Bgs[2][128 * 32];
  __shared__ __align__(16) unsigned short Bus[2][128 * 32];
  __shared__ int toks[128];

  const int tid = threadIdx.x;
  const int lane = tid & 63;
  const int w = tid >> 6;

  if (tid < 128) {
    int a = off + mblk * 128 + tid;
    if (a > NASSIGN - 1) a = NASSIGN - 1;
    toks[tid] = tok_of[a];
  }
  __syncthreads();

  const unsigned short* asrc[2];
  const unsigned short* bgsrc[2];
  const unsigned short* busrc[2];
#pragma unroll
  for (int j = 0; j < 2; ++j) {
    int rrow = w * 32 + j * 16 + (lane >> 2);
    int kcol = 8 * (lane & 3);
    asrc[j]  = xb  + (size_t)toks[rrow] * HID + kcol;
    bgsrc[j] = WgT + ((size_t)e * FFD + n0 + rrow) * HID + kcol;
    busrc[j] = WuT + ((size_t)e * FFD + n0 + rrow) * HID + kcol;
  }

  auto STAGE = [&](int buf, int k0) {
#pragma unroll
    for (int j = 0; j < 2; ++j) {
      gload16(asrc[j]  + k0, &As[buf][w * 1024 + j * 512]);
      gload16(bgsrc[j] + k0, &Bgs[buf][w * 1024 + j * 512]);
      gload16(busrc[j] + k0, &Bus[buf][w * 1024 + j * 512]);
    }
  };

  f32x4 accg[4][4] = {};
  f32x4 accu[4][4] = {};
  const int wr = (w >> 1) * 64, wc = (w & 1) * 64;
  const int lr = lane & 15, kg = (lane >> 4) * 8;

  STAGE(0, 0);                                 // prologue: 6 loads in flight
#pragma unroll 1
  for (int t = 0; t < HID / 32; ++t) {
    const int cur = t & 1;
    if (t + 1 < HID / 32) {
      STAGE(cur ^ 1, (t + 1) * 32);            // issue next tile (6 more loads)
      asm volatile("s_waitcnt vmcnt(6)" ::: "memory");   // tile t's 6 loads done
    } else {
      asm volatile("s_waitcnt vmcnt(0)" ::: "memory");
    }
    __builtin_amdgcn_s_barrier();              // buf[cur] ready for all waves

    bf16x8 af[4], bgf[4], buf_[4];
#pragma unroll
    for (int m = 0; m < 4; ++m)
      af[m] = *(const bf16x8*)&As[cur][(wr + m * 16 + lr) * 32 + kg];
#pragma unroll
    for (int n = 0; n < 4; ++n) {
      bgf[n]  = *(const bf16x8*)&Bgs[cur][(wc + n * 16 + lr) * 32 + kg];
      buf_[n] = *(const bf16x8*)&Bus[cur][(wc + n * 16 + lr) * 32 + kg];
    }
#pragma unroll
    for (int m = 0; m < 4; ++m)
#pragma unroll
      for (int n = 0; n < 4; ++n) {
        accg[m][n] = __builtin_amdgcn_mfma_f32_16x16x32_bf16(af[m], bgf[n],  accg[m][n], 0, 0, 0);
        accu[m][n] = __builtin_amdgcn_mfma_f32_16x16x32_bf16(af[m], buf_[n], accu[m][n], 0, 0, 0);
      }
    __builtin_amdgcn_s_barrier();              // reads of buf[cur] done before overwrite
  }

  const int crb = (lane >> 4) * 4, cc = lane & 15;
#pragma unroll
  for (int m = 0; m < 4; ++m)
#pragma unroll
    for (int n = 0; n < 4; ++n)
#pragma unroll
      for (int r = 0; r < 4; ++r) {
        int lrow = wr + m * 16 + crb + r;
        int grow = mblk * 128 + lrow;
        if (grow < cnt) {
          size_t a = (size_t)off + grow;
          float g = accg[m][n][r];
          float u = accu[m][n][r];
          float sg = g / (1.0f + __expf(-g));   // silu
          hbuf[a * FFD + (n0 + wc + n * 16 + cc)] = f2bf(sg * u);
        }
      }
}

// ---------------- down GEMM: r9 fine-ring 256x256 (best measured down) ----
// 256x256 tile halves BOTH re-read factors vs 128x128 (A: 8->4 n-tiles,
// B: per-m-tile 16->8) — down is re-read-traffic dominated since hb/Wd
// panels exceed the 4MiB per-XCD L2. Ring of 4 half-buffers, counted vmcnt,
// conflict-free swizzle (r9: bank-conflict = 0).

__global__ __launch_bounds__(512, 1) void moe_down_kernel(
    const unsigned short* __restrict__ hb,    // [A][F] bf16
    const unsigned short* __restrict__ WdT,   // [E][H][F] bf16
    const int* __restrict__ counts, const int* __restrict__ offsets,
    unsigned short* __restrict__ ypart)       // [A][H] bf16
{
  const int e = blockIdx.x & 7;
  const int mblk = blockIdx.x >> 3;
  const int cnt = counts[e];
  if (mblk * 256 >= cnt) return;
  const int off = offsets[e];
  const int n0 = blockIdx.y * 256;

  // half layout: A[0..8191] (256r x 32k), B[8192..16383] (256r x 32k)
  __shared__ __align__(16) unsigned short L[4][16384];   // 128 KiB ring

  const int tid = threadIdx.x;
  const int lane = tid & 63;
  const int w = tid >> 6;

  const int sr = tid >> 2, st = tid & 3;
  const int scol = ((st ^ ((sr >> 1) & 3)) << 3);        // bank-quad involution
  int ar0 = off + mblk * 256 + sr;       if (ar0 > NASSIGN - 1) ar0 = NASSIGN - 1;
  int ar1 = off + mblk * 256 + 128 + sr; if (ar1 > NASSIGN - 1) ar1 = NASSIGN - 1;
  const unsigned short* a0p = hb + (size_t)ar0 * FFD + scol;
  const unsigned short* a1p = hb + (size_t)ar1 * FFD + scol;
  const unsigned short* b0p = WdT + ((size_t)e * HID + n0 + sr) * FFD + scol;
  const unsigned short* b1p = WdT + ((size_t)e * HID + n0 + 128 + sr) * FFD + scol;

  auto SP0 = [&](int g) {                      // A rows 0-127, 128-255
    unsigned short* H = &L[g & 3][0];
    gload16(a0p + g * 32, H + tid * 8);
    gload16(a1p + g * 32, H + 4096 + tid * 8);
  };
  auto SP1 = [&](int g) {                      // B rows 0-127, 128-255
    unsigned short* H = &L[g & 3][0];
    gload16(b0p + g * 32, H + 8192 + tid * 8);
    gload16(b1p + g * 32, H + 12288 + tid * 8);
  };

  const int lr = lane & 15, lq = lane >> 4;
  const int rdswz = ((lq ^ ((lr >> 1) & 3)) << 3);
  const int wm = w >> 2, wn = w & 3;           // wave = 128r x 64c

  f32x4 acc[8][4] = {};

  SP0(0); SP1(0); SP0(1); SP1(1); SP0(2); SP1(2);

  const int NH = FFD / 32;   // 128 halves
  bf16x8 bf_[4];
#pragma unroll 4
  for (int g = 0; g < NH; ++g) {
    const unsigned short* H = &L[g & 3][0];
    const int rem = NH - 1 - g;
    if (rem >= 2)      asm volatile("s_waitcnt vmcnt(8)" ::: "memory");
    else if (rem == 1) asm volatile("s_waitcnt vmcnt(4)" ::: "memory");
    else               asm volatile("s_waitcnt vmcnt(0)" ::: "memory");
    __builtin_amdgcn_s_barrier();

    // ---- phase mh0
    bf16x8 af[4];
#pragma unroll
    for (int m = 0; m < 4; ++m)
      af[m] = *(const bf16x8*)(H + (wm * 128 + m * 16 + lr) * 32 + rdswz);
#pragma unroll
    for (int n = 0; n < 4; ++n)
      bf_[n] = *(const bf16x8*)(H + 8192 + (wn * 64 + n * 16 + lr) * 32 + rdswz);
    if (g + 3 < NH) SP0(g + 3);
    asm volatile("s_waitcnt lgkmcnt(0)" ::: "memory");
    __builtin_amdgcn_s_setprio(1);
#pragma unroll
    for (int m = 0; m < 4; ++m)
#pragma unroll
      for (int n = 0; n < 4; ++n)
        acc[m][n] = __builtin_amdgcn_mfma_f32_16x16x32_bf16(af[m], bf_[n], acc[m][n], 0, 0, 0);
    __builtin_amdgcn_s_setprio(0);
    __builtin_amdgcn_s_barrier();

    // ---- phase mh1
#pragma unroll
    for (int m = 0; m < 4; ++m)
      af[m] = *(const bf16x8*)(H + (wm * 128 + 64 + m * 16 + lr) * 32 + rdswz);
    if (g + 3 < NH) SP1(g + 3);
    __builtin_amdgcn_s_barrier();
    asm volatile("s_waitcnt lgkmcnt(0)" ::: "memory");
    __builtin_amdgcn_s_setprio(1);
#pragma unroll
    for (int m = 0; m < 4; ++m)
#pragma unroll
      for (int n = 0; n < 4; ++n)
        acc[4 + m][n] = __builtin_amdgcn_mfma_f32_16x16x32_bf16(af[m], bf_[n], acc[4 + m][n], 0, 0, 0);
    __builtin_amdgcn_s_setprio(0);
  }

  const int crb = (lane >> 4) * 4, cc = lane & 15;
#pragma unroll
  for (int m = 0; m < 8; ++m)
#pragma unroll
    for (int n = 0; n < 4; ++n)
#pragma unroll
      for (int r = 0; r < 4; ++r) {
        int lrow = wm * 128 + (m >> 2) * 64 + (m & 3) * 16 + crb + r;
        int grow = mblk * 256 + lrow;
        if (grow < cnt)
          ypart[((size_t)off + grow) * HID + (n0 + wn * 64 + n * 16 + cc)] = f2bf(acc[m][n][r]);
      }
}

__global__ void combine_kernel(const unsigned short* __restrict__ ypart,  // [A][H] bf16
                               const int* __restrict__ asn_of,
                               const float* __restrict__ wt_of,
                               float* __restrict__ y) {
  const int t = blockIdx.x;
  const int a0 = asn_of[t * 2], a1 = asn_of[t * 2 + 1];
  const float w0 = wt_of[a0], w1 = wt_of[a1];
  const int c = threadIdx.x * 4;
  ushort4 p0 = *(const ushort4*)&ypart[(size_t)a0 * HID + c];
  ushort4 p1 = *(const ushort4*)&ypart[(size_t)a1 * HID + c];
  float4 r;
  r.x = w0 * bf2f(p0.x) + w1 * bf2f(p1.x);
  r.y = w0 * bf2f(p0.y) + w1 * bf2f(p1.y);
  r.z = w0 * bf2f(p0.z) + w1 * bf2f(p1.z);
  r.w = w0 * bf2f(p0.w) + w1 * bf2f(p1.w);
  *(float4*)&y[(size_t)t * HID + c] = r;
}

// ---------------- launch ----------------

extern "C" void kernel_launch(void* const* d_in, const int* in_sizes, int n_in,
                              void* d_out, int out_size, void* d_ws, size_t ws_size,
                              hipStream_t stream) {
  const float* x  = (const float*)d_in[0];
  const float* gw = (const float*)d_in[1];
  const float* gb = (const float*)d_in[2];
  const float* Wg = (const float*)d_in[3];
  const float* Wu = (const float*)d_in[4];
  const float* Wd = (const float*)d_in[5];
  float* out = (float*)d_out;
  float* logits = out + (size_t)TTOK * HID;

  char* ws = (char*)d_ws;
  size_t o = 0;
  auto carve = [&](size_t b) { char* p = ws + o; o += (b + 255) & ~(size_t)255; return p; };
  int*   counts  = (int*)carve(NEXP * 4);
  int*   offsets = (int*)carve(NEXP * 4);
  int*   te      = (int*)carve((size_t)TTOK * 2 * 4);
  int*   tp      = (int*)carve((size_t)TTOK * 2 * 4);
  float* tw      = (float*)carve((size_t)TTOK * 2 * 4);
  int*   tok_of  = (int*)carve((size_t)NASSIGN * 4);
  float* wt_of   = (float*)carve((size_t)NASSIGN * 4);
  int*   asn_of  = (int*)carve((size_t)TTOK * 2 * 4);
  unsigned short* xb  = (unsigned short*)carve((size_t)TTOK * HID * 2);
  unsigned short* WgT = (unsigned short*)carve((size_t)NEXP * FFD * HID * 2);
  unsigned short* WuT = (unsigned short*)carve((size_t)NEXP * FFD * HID * 2);
  unsigned short* WdT = (unsigned short*)carve((size_t)NEXP * HID * FFD * 2);
  unsigned short* hb  = (unsigned short*)carve((size_t)NASSIGN * FFD * 2);
  unsigned short* ypart = (unsigned short*)carve((size_t)NASSIGN * HID * 2);
  (void)ws_size; (void)in_sizes; (void)n_in; (void)out_size;

  zero_counts_kernel<<<dim3(1), dim3(64), 0, stream>>>(counts);
  gate_kernel<<<dim3(TTOK / 4), dim3(256), 0, stream>>>(x, gw, gb, logits, counts, te, tp, tw, xb);
  scatter_kernel<<<dim3(1), dim3(256), 0, stream>>>(counts, offsets, te, tp, tw, tok_of, wt_of, asn_of);
  transpose_all_kernel<<<dim3(1024, 3, NEXP), dim3(256), 0, stream>>>(Wg, Wu, Wd, WgT, WuT, WdT);
  // up: grid.x = 8 experts * MAXMB 128-row m-tiles; x%8 = expert = XCD
  moe_up_kernel<<<dim3(NEXP * MAXMB, FFD / 128), dim3(256), 0, stream>>>(xb, WgT, WuT, counts, offsets, tok_of, hb);
  // down: grid.x = 8 experts * MCAP 256-row m-groups; grid.y = 1024/256
  moe_down_kernel<<<dim3(NEXP * MCAP, HID / 256), dim3(512), 0, stream>>>(hb, WdT, counts, offsets, ypart);
  combine_kernel<<<dim3(TTOK), dim3(256), 0, stream>>>(ypart, asn_of, wt_of, out);
}